// Round 21
// baseline (185.052 us; speedup 1.0000x reference)
//
#include <hip/hip_runtime.h>
#include <hip/hip_bf16.h>

// Problem: B=4, T=2048, D=1024, H=16, HD=64
#define B_  4
#define T_  2048
#define D_  1024
#define H_  16
#define HD_ 64

typedef short s16x8 __attribute__((ext_vector_type(8)));
typedef short s16x4 __attribute__((ext_vector_type(4)));
typedef float f32x4 __attribute__((ext_vector_type(4)));
typedef unsigned int u32x2 __attribute__((ext_vector_type(2)));

#define MFMA32(a, b, c) __builtin_amdgcn_mfma_f32_16x16x32_bf16(a, b, c, 0, 0, 0)
#define MFMA16(a, b, c) __builtin_amdgcn_mfma_f32_16x16x16bf16_1k(a, b, c, 0, 0, 0)

__device__ __forceinline__ unsigned short f2bf(float f) {
  unsigned u = __builtin_bit_cast(unsigned, f);
  u += 0x7fffu + ((u >> 16) & 1u);   // RNE
  return (unsigned short)(u >> 16);
}

__device__ __forceinline__ float bf2f(unsigned short h) {
  return __builtin_bit_cast(float, (unsigned)h << 16);
}

#define GLOAD_LDS16(src, dst)                                            \
  __builtin_amdgcn_global_load_lds(                                      \
      (__attribute__((address_space(1))) void*)(void*)(src),             \
      (__attribute__((address_space(3))) void*)(dst), 16, 0, 0)

// ---------------------------------------------------------------- convert x
__global__ __launch_bounds__(256) void convert_x_kernel(
    const float* __restrict__ in, unsigned short* __restrict__ out, int n8) {
  int i = blockIdx.x * 256 + threadIdx.x;
  if (i >= n8) return;
  const float4* p = ((const float4*)in) + (size_t)i * 2;
  float4 a = p[0], b = p[1];
  s16x8 o;
  o[0] = (short)f2bf(a.x); o[1] = (short)f2bf(a.y);
  o[2] = (short)f2bf(a.z); o[3] = (short)f2bf(a.w);
  o[4] = (short)f2bf(b.x); o[5] = (short)f2bf(b.y);
  o[6] = (short)f2bf(b.z); o[7] = (short)f2bf(b.w);
  *(((s16x8*)out) + i) = o;
}

// ------------------------------------------------- transpose W [K][N] -> bf16 [N][K]
__global__ __launch_bounds__(256) void transpose_w_kernel(
    const float* __restrict__ W, unsigned short* __restrict__ Wt, int K, int N) {
  __shared__ float tile[32][33];
  int n0 = blockIdx.x * 32, k0 = blockIdx.y * 32;
  int tx = threadIdx.x & 31, ty = threadIdx.x >> 5;  // ty 0..7
#pragma unroll
  for (int j = 0; j < 4; ++j) {
    int k = ty + j * 8;
    tile[k][tx] = W[(size_t)(k0 + k) * N + n0 + tx];
  }
  __syncthreads();
#pragma unroll
  for (int j = 0; j < 4; ++j) {
    int n = ty + j * 8;
    Wt[(size_t)(n0 + n) * K + k0 + tx] = f2bf(tile[tx][n]);
  }
}

// ---------------------------------------------------------------- GEMM 128x128
// r20-validated (FROZEN): 4-wave dbuf + counted vmcnt, both-sides octet-XOR
// swizzle (r12: conflicts 1.9e7 -> 0).
template <int OUTF32>
__global__ __launch_bounds__(256, 2) void gemm_kernel(
    const unsigned short* __restrict__ A, const unsigned short* __restrict__ Bt,
    const float* __restrict__ bias, void* __restrict__ Cout, int M, int N, int K) {
  __shared__ char lds[65536];  // 2 bufs x (A 16KB + B 16KB)
  const int n0 = blockIdx.x * 128, m0 = blockIdx.y * 128;
  const int w = threadIdx.x >> 6, lane = threadIdx.x & 63;
  const int l15 = lane & 15, g = lane >> 4;
  const int wr = w >> 1, wc = w & 1;
  const int srow = (lane >> 3);       // 0..7 within chunk (= row & 7)
  const int u = lane & 7;             // d-octet 0..7
  const int soct = (u ^ srow) << 3;   // inverse-swizzled source octet (elems)
  const int rx = l15 & 7;             // read-side row&7
  f32x4 acc[4][4] = {};

  auto stage = [&](int buf, int kt) {
    char* Ab = lds + buf * 32768;
    char* Bb = Ab + 16384;
#pragma unroll
    for (int i = 0; i < 4; ++i) {
      int c = w * 4 + i;              // chunk 0..15, 8 rows each
      int row = c * 8 + srow;         // 0..127 (row & 7 == srow)
      GLOAD_LDS16(A + (size_t)(m0 + row) * K + kt + soct, Ab + c * 1024);
      GLOAD_LDS16(Bt + (size_t)(n0 + row) * K + kt + soct, Bb + c * 1024);
    }
  };

  stage(0, 0);
  __syncthreads();  // prologue: drain buf0 fully
  int cur = 0;

  for (int kt = 0; kt < K; kt += 64) {
    // barrier A: all waves done READING cur^1 (prev compute) -> safe to overwrite
    __builtin_amdgcn_s_barrier();
    if (kt + 64 < K) {
      stage(cur ^ 1, kt + 64);  // 8 fresh loads fly across the next barrier
      asm volatile("s_waitcnt vmcnt(8)" ::: "memory");
    } else {
      asm volatile("s_waitcnt vmcnt(0)" ::: "memory");  // final tile: full drain
    }
    __builtin_amdgcn_s_barrier();   // barrier B: cur visible to all waves
    __builtin_amdgcn_sched_barrier(0);  // rule 18: pin reads after the wait
    const char* Al = lds + cur * 32768;
    const char* Bl = Al + 16384;
#pragma unroll
    for (int kk = 0; kk < 2; ++kk) {
      const int roct = ((kk * 4 + g) ^ rx) << 4;  // swizzled read octet (bytes)
      s16x8 af[4], bfr[4];
#pragma unroll
      for (int mi = 0; mi < 4; ++mi) {
        int row = wr * 64 + mi * 16 + l15;
        af[mi] = *(const s16x8*)(Al + row * 128 + roct);
      }
#pragma unroll
      for (int ni = 0; ni < 4; ++ni) {
        int row = wc * 64 + ni * 16 + l15;
        bfr[ni] = *(const s16x8*)(Bl + row * 128 + roct);
      }
#pragma unroll
      for (int mi = 0; mi < 4; ++mi)
#pragma unroll
        for (int ni = 0; ni < 4; ++ni)
          acc[mi][ni] = MFMA32(af[mi], bfr[ni], acc[mi][ni]);
    }
    cur ^= 1;
  }
  // epilogue: D layout col=lane&15, row=(lane>>4)*4+r
#pragma unroll
  for (int ni = 0; ni < 4; ++ni) {
    int col = n0 + wc * 64 + ni * 16 + l15;
    float bv = bias[col];
#pragma unroll
    for (int mi = 0; mi < 4; ++mi) {
      int row = m0 + wr * 64 + mi * 16 + g * 4;
#pragma unroll
      for (int r = 0; r < 4; ++r) {
        float v = acc[mi][ni][r] + bv;
        if (OUTF32)
          ((float*)Cout)[(size_t)(row + r) * N + col] = v;
        else
          ((unsigned short*)Cout)[(size_t)(row + r) * N + col] = f2bf(v);
      }
    }
  }
}

// ---------------------------------------------------------------- attention
// r13's validated 32q/wave compute (shared K/V LDS reads for two 16-q groups)
// + r16's validated unpaired-LPT grid: QBLK=128, 4 waves x 32q, grid
// (64 bh, 16 tiles) = 1024 blocks = 4/CU, qt = 15 - blockIdx.y (LPT).
// __launch_bounds__(256,4): cap 128 >= r13's measured 84 -> no spill.
// K: octet-XOR swizzle; V^T: stride-76 padded scatter; ones-MFMA row-sum;
// max3 tree; T13 defer-max; single-slot T14 prefetch.
#define VT_STR 76
#define VT_BLK 1232
__global__ __launch_bounds__(256, 4) void attn_kernel(
    const unsigned short* __restrict__ qkv, unsigned short* __restrict__ yatt) {
  __shared__ char lds[8192 + 4 * VT_BLK * 2];  // K 8KB + Vt 9856B; ylds aliases
  const int bh = blockIdx.x;          // 0..63
  const int qt = 15 - blockIdx.y;     // LPT: longest first
  const int b = bh >> 4, h = bh & 15;
  const int w = threadIdx.x >> 6;
  const int lane = threadIdx.x & 63;
  const int l15 = lane & 15, g = lane >> 4;

  const size_t rowstride = 3 * D_;  // 3072 elems per token row
  const unsigned short* Qb = qkv + (size_t)b * T_ * rowstride + h * HD_;
  const unsigned short* Kb = Qb + D_;
  const unsigned short* Vb = Qb + 2 * D_;

  char* Klds = lds;
  unsigned short* Vt = (unsigned short*)(lds + 8192);  // [4 blk][16 d][76 key]

  const int krow0 = (w * 2 + 0) * 8 + (lane >> 3);
  const int krow1 = (w * 2 + 1) * 8 + (lane >> 3);
  const int u = lane & 7;
  const int vkey = w * 16 + (lane >> 2);
  const int vdb = lane & 3;
  const float SC = 0.18033688011112042f;  // log2(e)/sqrt(64)
  const s16x4 onesf = {(short)0x3F80, (short)0x3F80, (short)0x3F80, (short)0x3F80};

  // single prefetch slot (T14)
  s16x8 kreg0, kreg1, vreg0, vreg1;
  auto ld = [&](int kt) {
    const unsigned short* kb = Kb + (size_t)(kt * 64) * rowstride;
    kreg0 = *(const s16x8*)(kb + (size_t)krow0 * rowstride + u * 8);
    kreg1 = *(const s16x8*)(kb + (size_t)krow1 * rowstride + u * 8);
    const unsigned short* vs = Vb + (size_t)(kt * 64 + vkey) * rowstride + vdb * 16;
    vreg0 = *(const s16x8*)(vs);
    vreg1 = *(const s16x8*)(vs + 8);
  };

  const int base = qt * 128 + w * 32;  // wave's first q row
  const int ntk = 2 * qt + 2;          // kv-iters

  // Q fragments, SC pre-folded; group A rows base+0..15, group B +16..31
  s16x8 qfA0, qfA1, qfB0, qfB1;
  {
    const unsigned short* qa = Qb + (size_t)(base + l15) * rowstride;
    const unsigned short* qb = Qb + (size_t)(base + 16 + l15) * rowstride;
    s16x8 a0 = *(const s16x8*)(qa + g * 8);
    s16x8 a1 = *(const s16x8*)(qa + 32 + g * 8);
    s16x8 b0 = *(const s16x8*)(qb + g * 8);
    s16x8 b1 = *(const s16x8*)(qb + 32 + g * 8);
#pragma unroll
    for (int j = 0; j < 8; ++j) {
      qfA0[j] = (short)f2bf(bf2f((unsigned short)a0[j]) * SC);
      qfA1[j] = (short)f2bf(bf2f((unsigned short)a1[j]) * SC);
      qfB0[j] = (short)f2bf(bf2f((unsigned short)b0[j]) * SC);
      qfB1[j] = (short)f2bf(bf2f((unsigned short)b1[j]) * SC);
    }
  }

  ld(0);
  float mA = -1e30f, mB = -1e30f;
  f32x4 accA[4] = {}, accB[4] = {};
  f32x4 accSA = {}, accSB = {};

#pragma unroll 1
  for (int kt = 0; kt < ntk; ++kt) {
    __syncthreads();
    // K: octet-XOR-swizzled write (reader applies same XOR -> identity)
    *(s16x8*)(Klds + krow0 * 128 + ((u ^ (krow0 & 7)) << 4)) = kreg0;
    *(s16x8*)(Klds + krow1 * 128 + ((u ^ (krow1 & 7)) << 4)) = kreg1;
    // V^T: block-padded scatter
#pragma unroll
    for (int j = 0; j < 8; ++j) {
      Vt[vdb * VT_BLK + j * VT_STR + vkey] = (unsigned short)vreg0[j];
      Vt[vdb * VT_BLK + (8 + j) * VT_STR + vkey] = (unsigned short)vreg1[j];
    }
    __syncthreads();
    // T14: reload slot for kt+1; latency hides under this iter's math
    if (kt < ntk - 1) ld(kt + 1);

    // wave guard (all 32 q of this wave fully masked?)
    if (kt * 64 > base + 31) continue;

    // QK^T: shared K-frag reads feed both q-groups
    float tvA[16], tvB[16];
    __builtin_amdgcn_s_setprio(1);
#pragma unroll
    for (int kk = 0; kk < 4; ++kk) {
      int key = kk * 16 + l15;
      const s16x8 kf0 = *(const s16x8*)(Klds + key * 128 + ((g ^ (key & 7)) << 4));
      const s16x8 kf1 = *(const s16x8*)(Klds + key * 128 + (((4 + g) ^ (key & 7)) << 4));
      f32x4 sA = {}, sB = {};
      sA = MFMA32(kf0, qfA0, sA);
      sA = MFMA32(kf1, qfA1, sA);
      sB = MFMA32(kf0, qfB0, sB);
      sB = MFMA32(kf1, qfB1, sB);
#pragma unroll
      for (int r = 0; r < 4; ++r) { tvA[kk * 4 + r] = sA[r]; tvB[kk * 4 + r] = sB[r]; }
    }
    __builtin_amdgcn_s_setprio(0);
    if (kt * 64 + 63 > base) {  // diagonal region: causal mask both groups
      int qA = base + l15, qB = base + 16 + l15;
#pragma unroll
      for (int kk = 0; kk < 4; ++kk)
#pragma unroll
        for (int r = 0; r < 4; ++r) {
          int key = kt * 64 + kk * 16 + g * 4 + r;
          if (key > qA) tvA[kk * 4 + r] = -1e30f;
          if (key > qB) tvB[kk * 4 + r] = -1e30f;
        }
    }
    s16x4 pbA[4], pbB[4];
    // ---- softmax group A
    {
      float a0 = fmaxf(fmaxf(tvA[0], tvA[1]), tvA[2]);
      float a1 = fmaxf(fmaxf(tvA[3], tvA[4]), tvA[5]);
      float a2 = fmaxf(fmaxf(tvA[6], tvA[7]), tvA[8]);
      float a3 = fmaxf(fmaxf(tvA[9], tvA[10]), tvA[11]);
      float a4 = fmaxf(fmaxf(tvA[12], tvA[13]), tvA[14]);
      float tm = fmaxf(fmaxf(fmaxf(a0, a1), a2), fmaxf(fmaxf(a3, a4), tvA[15]));
      tm = fmaxf(tm, __shfl_xor(tm, 16));
      tm = fmaxf(tm, __shfl_xor(tm, 32));
      if (!__all(tm - mA <= 8.0f)) {
        float mn = fmaxf(mA, tm);
        float corr = exp2f(mA - mn);
        mA = mn;
#pragma unroll
        for (int i = 0; i < 4; ++i) {
          accA[i][0] *= corr; accA[i][1] *= corr;
          accA[i][2] *= corr; accA[i][3] *= corr;
        }
        accSA[0] *= corr; accSA[1] *= corr; accSA[2] *= corr; accSA[3] *= corr;
      }
#pragma unroll
      for (int kk = 0; kk < 4; ++kk) {
        float p0 = exp2f(tvA[kk * 4 + 0] - mA), p1 = exp2f(tvA[kk * 4 + 1] - mA);
        float p2 = exp2f(tvA[kk * 4 + 2] - mA), p3 = exp2f(tvA[kk * 4 + 3] - mA);
        u32x2 pk;
        pk[0] = __builtin_amdgcn_perm(__builtin_bit_cast(unsigned, p1),
                                      __builtin_bit_cast(unsigned, p0), 0x07060302u);
        pk[1] = __builtin_amdgcn_perm(__builtin_bit_cast(unsigned, p3),
                                      __builtin_bit_cast(unsigned, p2), 0x07060302u);
        pbA[kk] = __builtin_bit_cast(s16x4, pk);
      }
    }
    // ---- softmax group B
    {
      float a0 = fmaxf(fmaxf(tvB[0], tvB[1]), tvB[2]);
      float a1 = fmaxf(fmaxf(tvB[3], tvB[4]), tvB[5]);
      float a2 = fmaxf(fmaxf(tvB[6], tvB[7]), tvB[8]);
      float a3 = fmaxf(fmaxf(tvB[9], tvB[10]), tvB[11]);
      float a4 = fmaxf(fmaxf(tvB[12], tvB[13]), tvB[14]);
      float tm = fmaxf(fmaxf(fmaxf(a0, a1), a2), fmaxf(fmaxf(a3, a4), tvB[15]));
      tm = fmaxf(tm, __shfl_xor(tm, 16));
      tm = fmaxf(tm, __shfl_xor(tm, 32));
      if (!__all(tm - mB <= 8.0f)) {
        float mn = fmaxf(mB, tm);
        float corr = exp2f(mB - mn);
        mB = mn;
#pragma unroll
        for (int i = 0; i < 4; ++i) {
          accB[i][0] *= corr; accB[i][1] *= corr;
          accB[i][2] *= corr; accB[i][3] *= corr;
        }
        accSB[0] *= corr; accSB[1] *= corr; accSB[2] *= corr; accSB[3] *= corr;
      }
#pragma unroll
      for (int kk = 0; kk < 4; ++kk) {
        float p0 = exp2f(tvB[kk * 4 + 0] - mB), p1 = exp2f(tvB[kk * 4 + 1] - mB);
        float p2 = exp2f(tvB[kk * 4 + 2] - mB), p3 = exp2f(tvB[kk * 4 + 3] - mB);
        u32x2 pk;
        pk[0] = __builtin_amdgcn_perm(__builtin_bit_cast(unsigned, p1),
                                      __builtin_bit_cast(unsigned, p0), 0x07060302u);
        pk[1] = __builtin_amdgcn_perm(__builtin_bit_cast(unsigned, p3),
                                      __builtin_bit_cast(unsigned, p2), 0x07060302u);
        pbB[kk] = __builtin_bit_cast(s16x4, pk);
      }
    }
    // PV: shared V-frag reads feed both q-groups; ones-MFMA row-sums
    __builtin_amdgcn_s_setprio(1);
#pragma unroll
    for (int kk = 0; kk < 4; ++kk) {
#pragma unroll
      for (int db = 0; db < 4; ++db) {
        s16x4 vf = *(const s16x4*)(Vt + db * VT_BLK + l15 * VT_STR + kk * 16 + g * 4);
        accA[db] = MFMA16(vf, pbA[kk], accA[db]);
        accB[db] = MFMA16(vf, pbB[kk], accB[db]);
      }
      accSA = MFMA16(onesf, pbA[kk], accSA);
      accSB = MFMA16(onesf, pbB[kk], accSB);
    }
    __builtin_amdgcn_s_setprio(0);
  }

  // epilogue: denominators + transpose y^T -> y via ylds[64][130]
  float invA = 1.0f / accSA[0];
  float invB = 1.0f / accSB[0];
  __syncthreads();
  unsigned short* ylds = (unsigned short*)lds;  // [64 d][130]
#pragma unroll
  for (int db = 0; db < 4; ++db)
#pragma unroll
    for (int r = 0; r < 4; ++r) {
      int d = db * 16 + g * 4 + r;
      ylds[d * 130 + w * 32 + l15] = f2bf(accA[db][r] * invA);
      ylds[d * 130 + w * 32 + 16 + l15] = f2bf(accB[db][r] * invB);
    }
  __syncthreads();
  {
    int qq = threadIdx.x >> 1;         // 0..127
    int dc = (threadIdx.x & 1) * 32;   // 0 or 32
    s16x8 o0, o1, o2, o3;
#pragma unroll
    for (int j = 0; j < 8; ++j) {
      o0[j] = (short)ylds[(dc + j) * 130 + qq];
      o1[j] = (short)ylds[(dc + 8 + j) * 130 + qq];
      o2[j] = (short)ylds[(dc + 16 + j) * 130 + qq];
      o3[j] = (short)ylds[(dc + 24 + j) * 130 + qq];
    }
    unsigned short* dst =
        yatt + (size_t)(b * T_ + qt * 128 + qq) * D_ + h * HD_ + dc;
    *(s16x8*)(dst) = o0;
    *(s16x8*)(dst + 8) = o1;
    *(s16x8*)(dst + 16) = o2;
    *(s16x8*)(dst + 24) = o3;
  }
}

// ---------------------------------------------------------------- launcher
extern "C" void kernel_launch(void* const* d_in, const int* in_sizes, int n_in,
                              void* d_out, int out_size, void* d_ws, size_t ws_size,
                              hipStream_t stream) {
  const float* x     = (const float*)d_in[0];
  const float* Wqkv  = (const float*)d_in[1];
  const float* bqkv  = (const float*)d_in[2];
  const float* Wproj = (const float*)d_in[3];
  const float* bproj = (const float*)d_in[4];
  float* out = (float*)d_out;

  // workspace layout (bf16 buffers), 72 MiB total; yb aliases xb (dead after gemm<0>)
  unsigned short* xb   = (unsigned short*)d_ws;              // [8192][1024]
  unsigned short* Wqb  = xb + (size_t)8192 * 1024;           // [3072][1024] (W_qkv^T)
  unsigned short* Wpb  = Wqb + (size_t)3072 * 1024;          // [1024][1024] (W_proj^T)
  unsigned short* qkvb = Wpb + (size_t)1024 * 1024;          // [8192][3072]
  unsigned short* yb   = xb;                                 // alias: x dead after gemm<0>

  convert_x_kernel<<<dim3(4096), dim3(256), 0, stream>>>(x, xb, 8192 * 1024 / 8);
  transpose_w_kernel<<<dim3(96, 32), dim3(256), 0, stream>>>(Wqkv, Wqb, 1024, 3072);
  transpose_w_kernel<<<dim3(32, 32), dim3(256), 0, stream>>>(Wproj, Wpb, 1024, 1024);
  gemm_kernel<0><<<dim3(24, 64), dim3(256), 0, stream>>>(xb, Wqb, bqkv, qkvb, 8192, 3072, 1024);
  attn_kernel<<<dim3(64, 16), dim3(256), 0, stream>>>(qkvb, yb);
  gemm_kernel<1><<<dim3(8, 64), dim3(256), 0, stream>>>(yb, Wpb, bproj, out, 8192, 1024, 1024);
}

// Round 23
// 170.069 us; speedup vs baseline: 1.0881x; 1.0881x over previous
//
#include <hip/hip_runtime.h>
#include <hip/hip_bf16.h>

// Problem: B=4, T=2048, D=1024, H=16, HD=64
#define B_  4
#define T_  2048
#define D_  1024
#define H_  16
#define HD_ 64

typedef short s16x8 __attribute__((ext_vector_type(8)));
typedef short s16x4 __attribute__((ext_vector_type(4)));
typedef float f32x4 __attribute__((ext_vector_type(4)));
typedef unsigned int u32x2 __attribute__((ext_vector_type(2)));

#define MFMA32(a, b, c) __builtin_amdgcn_mfma_f32_16x16x32_bf16(a, b, c, 0, 0, 0)
#define MFMA16(a, b, c) __builtin_amdgcn_mfma_f32_16x16x16bf16_1k(a, b, c, 0, 0, 0)

__device__ __forceinline__ unsigned short f2bf(float f) {
  unsigned u = __builtin_bit_cast(unsigned, f);
  u += 0x7fffu + ((u >> 16) & 1u);   // RNE
  return (unsigned short)(u >> 16);
}

__device__ __forceinline__ float bf2f(unsigned short h) {
  return __builtin_bit_cast(float, (unsigned)h << 16);
}

#define GLOAD_LDS16(src, dst)                                            \
  __builtin_amdgcn_global_load_lds(                                      \
      (__attribute__((address_space(1))) void*)(void*)(src),             \
      (__attribute__((address_space(3))) void*)(dst), 16, 0, 0)

// ---------------------------------------------------------------- convert x
__global__ __launch_bounds__(256) void convert_x_kernel(
    const float* __restrict__ in, unsigned short* __restrict__ out, int n8) {
  int i = blockIdx.x * 256 + threadIdx.x;
  if (i >= n8) return;
  const float4* p = ((const float4*)in) + (size_t)i * 2;
  float4 a = p[0], b = p[1];
  s16x8 o;
  o[0] = (short)f2bf(a.x); o[1] = (short)f2bf(a.y);
  o[2] = (short)f2bf(a.z); o[3] = (short)f2bf(a.w);
  o[4] = (short)f2bf(b.x); o[5] = (short)f2bf(b.y);
  o[6] = (short)f2bf(b.z); o[7] = (short)f2bf(b.w);
  *(((s16x8*)out) + i) = o;
}

// ------------------------------------------------- transpose W [K][N] -> bf16 [N][K]
__global__ __launch_bounds__(256) void transpose_w_kernel(
    const float* __restrict__ W, unsigned short* __restrict__ Wt, int K, int N) {
  __shared__ float tile[32][33];
  int n0 = blockIdx.x * 32, k0 = blockIdx.y * 32;
  int tx = threadIdx.x & 31, ty = threadIdx.x >> 5;  // ty 0..7
#pragma unroll
  for (int j = 0; j < 4; ++j) {
    int k = ty + j * 8;
    tile[k][tx] = W[(size_t)(k0 + k) * N + n0 + tx];
  }
  __syncthreads();
#pragma unroll
  for (int j = 0; j < 4; ++j) {
    int n = ty + j * 8;
    Wt[(size_t)(n0 + n) * K + k0 + tx] = f2bf(tile[tx][n]);
  }
}

// ---------------------------------------------------------------- GEMM 128x128
// r17-validated (best total 172.7): T3 minimum-2-phase double-buffered LDS,
// STAGE(next) before compute(cur), one __syncthreads per K-step. Both-sides
// octet-XOR swizzle (r12: conflicts 1.9e7 -> 0).
template <int OUTF32>
__global__ __launch_bounds__(256, 2) void gemm_kernel(
    const unsigned short* __restrict__ A, const unsigned short* __restrict__ Bt,
    const float* __restrict__ bias, void* __restrict__ Cout, int M, int N, int K) {
  __shared__ char lds[65536];  // 2 bufs x (A 16KB + B 16KB)
  const int n0 = blockIdx.x * 128, m0 = blockIdx.y * 128;
  const int w = threadIdx.x >> 6, lane = threadIdx.x & 63;
  const int l15 = lane & 15, g = lane >> 4;
  const int wr = w >> 1, wc = w & 1;
  const int srow = (lane >> 3);       // 0..7 within chunk (= row & 7)
  const int u = lane & 7;             // d-octet 0..7
  const int soct = (u ^ srow) << 3;   // inverse-swizzled source octet (elems)
  const int rx = l15 & 7;             // read-side row&7
  f32x4 acc[4][4] = {};

  auto stage = [&](int buf, int kt) {
    char* Ab = lds + buf * 32768;
    char* Bb = Ab + 16384;
#pragma unroll
    for (int i = 0; i < 4; ++i) {
      int c = w * 4 + i;              // chunk 0..15, 8 rows each
      int row = c * 8 + srow;         // 0..127 (row & 7 == srow)
      GLOAD_LDS16(A + (size_t)(m0 + row) * K + kt + soct, Ab + c * 1024);
      GLOAD_LDS16(Bt + (size_t)(n0 + row) * K + kt + soct, Bb + c * 1024);
    }
  };

  stage(0, 0);
  __syncthreads();  // prologue: buf0 resident
  int cur = 0;

  for (int kt = 0; kt < K; kt += 64) {
    if (kt + 64 < K) stage(cur ^ 1, kt + 64);  // prefetch flies under compute
    const char* Al = lds + cur * 32768;
    const char* Bl = Al + 16384;
#pragma unroll
    for (int kk = 0; kk < 2; ++kk) {
      const int roct = ((kk * 4 + g) ^ rx) << 4;  // swizzled read octet (bytes)
      s16x8 af[4], bfr[4];
#pragma unroll
      for (int mi = 0; mi < 4; ++mi) {
        int row = wr * 64 + mi * 16 + l15;
        af[mi] = *(const s16x8*)(Al + row * 128 + roct);
      }
#pragma unroll
      for (int ni = 0; ni < 4; ++ni) {
        int row = wc * 64 + ni * 16 + l15;
        bfr[ni] = *(const s16x8*)(Bl + row * 128 + roct);
      }
#pragma unroll
      for (int mi = 0; mi < 4; ++mi)
#pragma unroll
        for (int ni = 0; ni < 4; ++ni)
          acc[mi][ni] = MFMA32(af[mi], bfr[ni], acc[mi][ni]);
    }
    __syncthreads();  // drains prefetch (vmcnt0) + fences readers of cur
    cur ^= 1;
  }
  // epilogue: D layout col=lane&15, row=(lane>>4)*4+r
#pragma unroll
  for (int ni = 0; ni < 4; ++ni) {
    int col = n0 + wc * 64 + ni * 16 + l15;
    float bv = bias[col];
#pragma unroll
    for (int mi = 0; mi < 4; ++mi) {
      int row = m0 + wr * 64 + mi * 16 + g * 4;
#pragma unroll
      for (int r = 0; r < 4; ++r) {
        float v = acc[mi][ni][r] + bv;
        if (OUTF32)
          ((float*)Cout)[(size_t)(row + r) * N + col] = v;
        else
          ((unsigned short*)Cout)[(size_t)(row + r) * N + col] = f2bf(v);
      }
    }
  }
}

// ---------------------------------------------------------------- attention
// r16 structure (best attn: 83.3us); V staged 2-keys-x-8d per thread, scatter
// = 8 x ds_write_b32 (was 16 x b16). r22 BUGFIX: write address now uses the
// block-padded layout db*VT_BLK + d15*VT_STR (r22 used flat d*VT_STR and
// missed the 16-elem inter-block pad -> absmax 5.0). d = voct*8+j decomposes
// as db = voct>>1, d15 = (voct&1)*8+j (j<8 never crosses a 16-row block).
// PV read path unchanged (l15*76%4==0 -> b64 aligned; 6*l15 injective mod 32).
// Grid (64 bh, 32 y), qt=31-y (LPT), (256,5). K octet-XOR swizzle; ones-MFMA
// row-sum; max3 tree; T13 defer-max; single-slot T14 prefetch.
#define VT_STR 76
#define VT_BLK 1232
__global__ __launch_bounds__(256, 5) void attn_kernel(
    const unsigned short* __restrict__ qkv, unsigned short* __restrict__ yatt) {
  __shared__ char lds[8192 + 4 * VT_BLK * 2];  // K 8KB + Vt 9856B; ylds aliases
  const int bh = blockIdx.x;          // 0..63
  const int qt = 31 - blockIdx.y;     // LPT: longest first
  const int b = bh >> 4, h = bh & 15;
  const int w = threadIdx.x >> 6;
  const int lane = threadIdx.x & 63;
  const int l15 = lane & 15, g = lane >> 4;

  const size_t rowstride = 3 * D_;  // 3072 elems per token row
  const unsigned short* Qb = qkv + (size_t)b * T_ * rowstride + h * HD_;
  const unsigned short* Kb = Qb + D_;
  const unsigned short* Vb = Qb + 2 * D_;

  char* Klds = lds;
  unsigned short* Vt = (unsigned short*)(lds + 8192);  // [4 blk][16 d][76 key]+pad

  const int krow0 = (w * 2 + 0) * 8 + (lane >> 3);
  const int krow1 = (w * 2 + 1) * 8 + (lane >> 3);
  const int u = lane & 7;
  const int vkp = w * 8 + (lane >> 3);  // key-pair 0..31 -> keys 2vkp, 2vkp+1
  const int voct = lane & 7;            // d-octet: d = voct*8 + j
  const int vdb = voct >> 1;            // d-block 0..3
  const int vd15 = (voct & 1) * 8;      // d15 base within block
  const float SC = 0.18033688011112042f;  // log2(e)/sqrt(64)
  const s16x4 onesf = {(short)0x3F80, (short)0x3F80, (short)0x3F80, (short)0x3F80};

  // single prefetch slot (T14)
  s16x8 kreg0, kreg1, vreg0, vreg1;
  auto ld = [&](int kt) {
    const unsigned short* kb = Kb + (size_t)(kt * 64) * rowstride;
    kreg0 = *(const s16x8*)(kb + (size_t)krow0 * rowstride + u * 8);
    kreg1 = *(const s16x8*)(kb + (size_t)krow1 * rowstride + u * 8);
    const unsigned short* vs =
        Vb + (size_t)(kt * 64 + 2 * vkp) * rowstride + voct * 8;
    vreg0 = *(const s16x8*)(vs);               // key 2vkp,   d voct*8..+7
    vreg1 = *(const s16x8*)(vs + rowstride);   // key 2vkp+1, d voct*8..+7
  };

  // Q fragments with SC pre-folded (B operand: col=l15 -> q row, k=g*8+j -> d)
  s16x8 qf0, qf1;
  {
    const unsigned short* qr = Qb + (size_t)(qt * 64 + w * 16 + l15) * rowstride;
    s16x8 a0 = *(const s16x8*)(qr + g * 8);
    s16x8 a1 = *(const s16x8*)(qr + 32 + g * 8);
#pragma unroll
    for (int j = 0; j < 8; ++j) {
      qf0[j] = (short)f2bf(bf2f((unsigned short)a0[j]) * SC);
      qf1[j] = (short)f2bf(bf2f((unsigned short)a1[j]) * SC);
    }
  }

  ld(0);
  float m = -1e30f;
  f32x4 acc[4] = {};  // y^T: acc[db] holds d = db*16 + g*4 + r, q col = l15
  f32x4 accS = {};    // ones-row running sum of P

#pragma unroll 1
  for (int kt = 0; kt <= qt; ++kt) {
    __syncthreads();
    // K: octet-XOR-swizzled write (reader applies same XOR -> identity)
    *(s16x8*)(Klds + krow0 * 128 + ((u ^ (krow0 & 7)) << 4)) = kreg0;
    *(s16x8*)(Klds + krow1 * 128 + ((u ^ (krow1 & 7)) << 4)) = kreg1;
    // V^T: packed key-pair b32 writes into the BLOCK-PADDED layout
#pragma unroll
    for (int j = 0; j < 8; ++j) {
      unsigned pk = (unsigned)(unsigned short)vreg0[j] |
                    ((unsigned)(unsigned short)vreg1[j] << 16);
      *(unsigned*)(Vt + vdb * VT_BLK + (vd15 + j) * VT_STR + 2 * vkp) = pk;
    }
    __syncthreads();
    // T14: reload the slot for kt+1; HBM latency hides under this iter's math
    if (kt < qt) ld(kt + 1);

    // QK^T
    float tv[16];
    __builtin_amdgcn_s_setprio(1);
#pragma unroll
    for (int kk = 0; kk < 4; ++kk) {
      int key = kk * 16 + l15;
      const s16x8 kf0 = *(const s16x8*)(Klds + key * 128 + ((g ^ (key & 7)) << 4));
      const s16x8 kf1 = *(const s16x8*)(Klds + key * 128 + (((4 + g) ^ (key & 7)) << 4));
      f32x4 s = {};
      s = MFMA32(kf0, qf0, s);
      s = MFMA32(kf1, qf1, s);
#pragma unroll
      for (int r = 0; r < 4; ++r) tv[kk * 4 + r] = s[r];
    }
    __builtin_amdgcn_s_setprio(0);
    if (kt == qt) {  // diagonal tile: causal mask
      int q = qt * 64 + w * 16 + l15;
#pragma unroll
      for (int kk = 0; kk < 4; ++kk)
#pragma unroll
        for (int r = 0; r < 4; ++r)
          if (kt * 64 + kk * 16 + g * 4 + r > q) tv[kk * 4 + r] = -1e30f;
    }
    // max3-friendly tree reduce + cross-lane
    float a0 = fmaxf(fmaxf(tv[0], tv[1]), tv[2]);
    float a1 = fmaxf(fmaxf(tv[3], tv[4]), tv[5]);
    float a2 = fmaxf(fmaxf(tv[6], tv[7]), tv[8]);
    float a3 = fmaxf(fmaxf(tv[9], tv[10]), tv[11]);
    float a4 = fmaxf(fmaxf(tv[12], tv[13]), tv[14]);
    float b0 = fmaxf(fmaxf(a0, a1), a2);
    float b1 = fmaxf(fmaxf(a3, a4), tv[15]);
    float tm = fmaxf(b0, b1);
    tm = fmaxf(tm, __shfl_xor(tm, 16));
    tm = fmaxf(tm, __shfl_xor(tm, 32));
    if (!__all(tm - m <= 8.0f)) {  // T13 defer-max: P bounded by 2^8
      float mn = fmaxf(m, tm);
      float corr = exp2f(m - mn);
      m = mn;
#pragma unroll
      for (int i = 0; i < 4; ++i) {
        acc[i][0] *= corr; acc[i][1] *= corr;
        acc[i][2] *= corr; acc[i][3] *= corr;
      }
      accS[0] *= corr; accS[1] *= corr; accS[2] *= corr; accS[3] *= corr;
    }
    s16x4 pb[4];
#pragma unroll
    for (int kk = 0; kk < 4; ++kk) {
      float p0 = exp2f(tv[kk * 4 + 0] - m), p1 = exp2f(tv[kk * 4 + 1] - m);
      float p2 = exp2f(tv[kk * 4 + 2] - m), p3 = exp2f(tv[kk * 4 + 3] - m);
      u32x2 pk;  // truncation-pack two hi16s per v_perm
      pk[0] = __builtin_amdgcn_perm(__builtin_bit_cast(unsigned, p1),
                                    __builtin_bit_cast(unsigned, p0), 0x07060302u);
      pk[1] = __builtin_amdgcn_perm(__builtin_bit_cast(unsigned, p3),
                                    __builtin_bit_cast(unsigned, p2), 0x07060302u);
      pb[kk] = __builtin_bit_cast(s16x4, pk);
    }
    // PV: y^T += mfma(A = Vt fragment, B = P^T); row-sum via ones-A MFMA
    __builtin_amdgcn_s_setprio(1);
#pragma unroll
    for (int kk = 0; kk < 4; ++kk) {
#pragma unroll
      for (int db = 0; db < 4; ++db) {
        s16x4 vf = *(const s16x4*)(Vt + db * VT_BLK + l15 * VT_STR + kk * 16 + g * 4);
        acc[db] = MFMA16(vf, pb[kk], acc[db]);
      }
      accS = MFMA16(onesf, pb[kk], accS);
    }
    __builtin_amdgcn_s_setprio(0);
  }

  // epilogue: denom = accS (full row-sum in every lane) + transpose via LDS
  float inv = 1.0f / accS[0];
  __syncthreads();
  unsigned short* ylds = (unsigned short*)lds;  // [64 d][66]
#pragma unroll
  for (int db = 0; db < 4; ++db)
#pragma unroll
    for (int r = 0; r < 4; ++r)
      ylds[(db * 16 + g * 4 + r) * 66 + w * 16 + l15] = f2bf(acc[db][r] * inv);
  __syncthreads();
  int qq = threadIdx.x >> 2;
  int dc = (threadIdx.x & 3) * 16;
  s16x8 o1, o2;
#pragma unroll
  for (int j = 0; j < 8; ++j) {
    o1[j] = (short)ylds[(dc + j) * 66 + qq];
    o2[j] = (short)ylds[(dc + 8 + j) * 66 + qq];
  }
  unsigned short* dst = yatt + (size_t)(b * T_ + qt * 64 + qq) * D_ + h * HD_ + dc;
  *(s16x8*)(dst) = o1;
  *(s16x8*)(dst + 8) = o2;
}

// ---------------------------------------------------------------- launcher
extern "C" void kernel_launch(void* const* d_in, const int* in_sizes, int n_in,
                              void* d_out, int out_size, void* d_ws, size_t ws_size,
                              hipStream_t stream) {
  const float* x     = (const float*)d_in[0];
  const float* Wqkv  = (const float*)d_in[1];
  const float* bqkv  = (const float*)d_in[2];
  const float* Wproj = (const float*)d_in[3];
  const float* bproj = (const float*)d_in[4];
  float* out = (float*)d_out;

  // workspace layout (bf16 buffers), 72 MiB total; yb aliases xb (dead after gemm<0>)
  unsigned short* xb   = (unsigned short*)d_ws;              // [8192][1024]
  unsigned short* Wqb  = xb + (size_t)8192 * 1024;           // [3072][1024] (W_qkv^T)
  unsigned short* Wpb  = Wqb + (size_t)3072 * 1024;          // [1024][1024] (W_proj^T)
  unsigned short* qkvb = Wpb + (size_t)1024 * 1024;          // [8192][3072]
  unsigned short* yb   = xb;                                 // alias: x dead after gemm<0>

  convert_x_kernel<<<dim3(4096), dim3(256), 0, stream>>>(x, xb, 8192 * 1024 / 8);
  transpose_w_kernel<<<dim3(96, 32), dim3(256), 0, stream>>>(Wqkv, Wqb, 1024, 3072);
  transpose_w_kernel<<<dim3(32, 32), dim3(256), 0, stream>>>(Wproj, Wpb, 1024, 1024);
  gemm_kernel<0><<<dim3(24, 64), dim3(256), 0, stream>>>(xb, Wqb, bqkv, qkvb, 8192, 3072, 1024);
  attn_kernel<<<dim3(64, 32), dim3(256), 0, stream>>>(qkvb, yb);
  gemm_kernel<1><<<dim3(8, 64), dim3(256), 0, stream>>>(yb, Wpb, bproj, out, 8192, 1024, 1024);
}